// Round 10
// baseline (2467.925 us; speedup 1.0000x reference)
//
#include <hip/hip_runtime.h>
#include <hip/hip_bf16.h>
#include <stdint.h>

// B,S,H,I = 4,2048,4096,11008 ; M = B*S = 8192
static constexpr int Hd = 4096;
static constexpr int Id = 11008;
static constexpr int Md = 8192;

using short8 = __attribute__((ext_vector_type(8))) short;
using f32x4  = __attribute__((ext_vector_type(4))) float;

__device__ __forceinline__ unsigned short f2bf(float x) {
    union { float f; unsigned u; } v; v.f = x;
    unsigned r = v.u + 0x7FFF + ((v.u >> 16) & 1);   // RNE
    return (unsigned short)(r >> 16);
}

typedef const __attribute__((address_space(1))) unsigned int* as1_u32p;
typedef __attribute__((address_space(3))) unsigned int* as3_u32p;

__device__ __forceinline__ void gload16(const unsigned short* g, unsigned short* l) {
    __builtin_amdgcn_global_load_lds((as1_u32p)(const void*)g, (as3_u32p)(void*)l, 16, 0, 0);
}

// BK=32 tile stored row-folded: logical [R][32] bf16 -> phys [R/2][64].
// chunk(r,kc) = (r&63)*8 + ((kc + 4*(r>>6)) ^ (r&7)), kc = k/8 in 0..3.
// This reproduces the verified 8-chunk XOR geometry (0 bank conflicts).
#define AOFF32(r, kc) ((((r) & 63) * 8 + ((((kc) + 4 * ((r) >> 6))) ^ ((r) & 7))) * 8)

// inverse: phys chunk c (0..511) -> (logical row r, k-chunk kc)
__device__ __forceinline__ void chunk_src(int c, int& r, int& kc) {
    const int rlow = c >> 3, q = c & 7;
    const int w = q ^ (rlow & 7);
    r  = rlow + ((w >> 2) << 6);
    kc = w & 3;
}

#define LGKM0() do { asm volatile("s_waitcnt lgkmcnt(0)" ::: "memory"); \
                     __builtin_amdgcn_sched_barrier(0); } while (0)
#define VMCNT(n) do { asm volatile("s_waitcnt vmcnt(" #n ")" ::: "memory"); \
                      __builtin_amdgcn_sched_barrier(0); } while (0)
#define BARRIER() do { asm volatile("" ::: "memory"); __builtin_amdgcn_s_barrier(); \
                       asm volatile("" ::: "memory"); } while (0)

// ---------------------------------------------------------------------------
// fp32 -> bf16 bulk converter: all 4 tensors in one launch
// ---------------------------------------------------------------------------
__global__ __launch_bounds__(256) void k_cvt4(
    const float* __restrict__ s0, unsigned short* __restrict__ d0, int n0,
    const float* __restrict__ s1, unsigned short* __restrict__ d1, int n1,
    const float* __restrict__ s2, unsigned short* __restrict__ d2, int n2,
    const float* __restrict__ s3, unsigned short* __restrict__ d3, int n3)
{
    const int total = n0 + n1 + n2 + n3;
    int i = blockIdx.x * blockDim.x + threadIdx.x;
    const int stride = gridDim.x * blockDim.x;
    for (; i < total; i += stride) {
        const float* s; unsigned short* d; int j = i;
        if (j < n0) { s = s0; d = d0; }
        else { j -= n0;
            if (j < n1) { s = s1; d = d1; }
            else { j -= n1;
                if (j < n2) { s = s2; d = d2; }
                else { j -= n2; s = s3; d = d3; }
            }
        }
        f32x4 a = *(const f32x4*)(s + (size_t)j * 8);
        f32x4 b = *(const f32x4*)(s + (size_t)j * 8 + 4);
        short8 v;
        v[0] = (short)f2bf(a[0]); v[1] = (short)f2bf(a[1]);
        v[2] = (short)f2bf(a[2]); v[3] = (short)f2bf(a[3]);
        v[4] = (short)f2bf(b[0]); v[5] = (short)f2bf(b[1]);
        v[6] = (short)f2bf(b[2]); v[7] = (short)f2bf(b[3]);
        *reinterpret_cast<short8*>(d + (size_t)j * 8) = v;
    }
}

// ===========================================================================
// FUSED up+gate: inter = silu(x.wg^T) * (x.wu^T)
// 128(m)x128(i) tile, BK=32, 256 thr / 4 waves (wave wn = 32-col slice),
// 2 blocks/CU (48 KiB LDS, <=256 VGPR). 2 phases per K-tile:
//   P1: ds af(8)+gf(2); stage U(t+1)->Us[D^1]; bar; lgkm0; MFMA G x16; bar.
//   P2: ds uf(2); stage G(t+2)->Gs[D], A(t+2)->As[D]; bar; lgkm0;
//       MFMA U x16; vmcnt(4); bar.
// Reader map: Gs[D],As[D] read only P1 -> staged P2 (after P1-end barrier);
// Us[D] read only P2 -> staged next-tile P1 (i.e. Us[D^1] this P1). Race-free.
// vmcnt(4): waits tile t+1's 6 loads' predecessors; leaves G,A(t+2) in flight.
// ===========================================================================
template<int D>
__device__ __forceinline__ void ug_body(
    unsigned short (&As)[2][4096], unsigned short (&Gs)[2][4096], unsigned short (&Us)[2][4096],
    const unsigned short* pA0, const unsigned short* pA1,
    const unsigned short* pG0, const unsigned short* pG1,
    const unsigned short* pU0, const unsigned short* pU1,
    int stU, int stGA, bool pfU, bool pfGA,
    int wn, int r16, int kg, int wave,
    f32x4 (&ag)[8][2], f32x4 (&au)[8][2])
{
    short8 af[8], gf[2], uf[2];

    // ---- P1 ----
    #pragma unroll
    for (int mi = 0; mi < 8; ++mi)
        af[mi] = *(const short8*)&As[D][AOFF32(mi * 16 + r16, kg)];
    #pragma unroll
    for (int ni = 0; ni < 2; ++ni)
        gf[ni] = *(const short8*)&Gs[D][AOFF32(wn * 32 + ni * 16 + r16, kg)];
    if (pfU) {
        gload16(pU0 + stU, &Us[D ^ 1][wave * 512]);
        gload16(pU1 + stU, &Us[D ^ 1][2048 + wave * 512]);
    }
    BARRIER();
    LGKM0();
    __builtin_amdgcn_s_setprio(1);
    #pragma unroll
    for (int mi = 0; mi < 8; ++mi)
        #pragma unroll
        for (int ni = 0; ni < 2; ++ni)
            ag[mi][ni] = __builtin_amdgcn_mfma_f32_16x16x32_bf16(af[mi], gf[ni], ag[mi][ni], 0, 0, 0);
    __builtin_amdgcn_s_setprio(0);
    BARRIER();

    // ---- P2 ----
    #pragma unroll
    for (int ni = 0; ni < 2; ++ni)
        uf[ni] = *(const short8*)&Us[D][AOFF32(wn * 32 + ni * 16 + r16, kg)];
    if (pfGA) {
        gload16(pG0 + stGA, &Gs[D][wave * 512]);
        gload16(pG1 + stGA, &Gs[D][2048 + wave * 512]);
        gload16(pA0 + stGA, &As[D][wave * 512]);
        gload16(pA1 + stGA, &As[D][2048 + wave * 512]);
    }
    BARRIER();
    LGKM0();
    __builtin_amdgcn_s_setprio(1);
    #pragma unroll
    for (int mi = 0; mi < 8; ++mi)
        #pragma unroll
        for (int ni = 0; ni < 2; ++ni)
            au[mi][ni] = __builtin_amdgcn_mfma_f32_16x16x32_bf16(af[mi], uf[ni], au[mi][ni], 0, 0, 0);
    __builtin_amdgcn_s_setprio(0);
    if (pfGA) { VMCNT(4); }
    else      { VMCNT(0); }
    BARRIER();
}

__global__ __launch_bounds__(256, 2) void k_upgate(
    const unsigned short* __restrict__ A,   // xb  [Md][Hd]
    const unsigned short* __restrict__ G,   // wgb [Id][Hd]
    const unsigned short* __restrict__ U,   // wub [Id][Hd]
    unsigned short* __restrict__ inter)     // [Md][Id]
{
    __shared__ unsigned short As[2][4096];  // 16 KiB (dbuf x 128x32)
    __shared__ unsigned short Gs[2][4096];  // 16 KiB
    __shared__ unsigned short Us[2][4096];  // 16 KiB

    const int tid  = threadIdx.x;
    const int wave = tid >> 6;
    const int lane = tid & 63;
    const int wn   = wave;               // 0..3 -> cols wn*32
    const int r16  = lane & 15;
    const int kg   = lane >> 4;

    // raster: XCD chunk (688 = one m-group of 8 x 86 n); m fastest in group.
    const int nwg = gridDim.x;           // 5504 = 64m x 86n
    const int bid = blockIdx.x;
    const int swz = (bid & 7) * (nwg >> 3) + (bid >> 3);
    const int grp = swz / 688;
    const int rem = swz % 688;
    const int m0  = (grp * 8 + (rem & 7)) * 128;
    const int n0  = (rem >> 3) * 128;

    // staging sources: pass p covers phys chunks p*256+tid
    int r0_, kc0_, r1_, kc1_;
    chunk_src(tid, r0_, kc0_);
    chunk_src(256 + tid, r1_, kc1_);
    const unsigned short* pA0 = A + (size_t)(m0 + r0_) * Hd + kc0_ * 8;
    const unsigned short* pA1 = A + (size_t)(m0 + r1_) * Hd + kc1_ * 8;
    const unsigned short* pG0 = G + (size_t)(n0 + r0_) * Hd + kc0_ * 8;
    const unsigned short* pG1 = G + (size_t)(n0 + r1_) * Hd + kc1_ * 8;
    const unsigned short* pU0 = U + (size_t)(n0 + r0_) * Hd + kc0_ * 8;
    const unsigned short* pU1 = U + (size_t)(n0 + r1_) * Hd + kc1_ * 8;

    f32x4 ag[8][2] = {};
    f32x4 au[8][2] = {};

    constexpr int NT = Hd >> 5;   // 128 (even)

    // prologue: A,G,U(0)->bufs[0]; A,G(1)->bufs[1]  (U(1) staged at t=0 P1)
    gload16(pA0, &As[0][wave * 512]);  gload16(pA1, &As[0][2048 + wave * 512]);
    gload16(pG0, &Gs[0][wave * 512]);  gload16(pG1, &Gs[0][2048 + wave * 512]);
    gload16(pU0, &Us[0][wave * 512]);  gload16(pU1, &Us[0][2048 + wave * 512]);
    gload16(pA0 + 32, &As[1][wave * 512]);  gload16(pA1 + 32, &As[1][2048 + wave * 512]);
    gload16(pG0 + 32, &Gs[1][wave * 512]);  gload16(pG1 + 32, &Gs[1][2048 + wave * 512]);
    VMCNT(4);      // tile 0's 6 loads landed; tile 1's 4 in flight
    BARRIER();

    for (int kt = 0; kt < NT; kt += 2) {
        // body0 = tile kt (D=0): U(kt+1) off +32; G,A(kt+2) off +64
        ug_body<0>(As, Gs, Us, pA0, pA1, pG0, pG1, pU0, pU1,
                   32, 64, true, (kt + 2) < NT, wn, r16, kg, wave, ag, au);
        // body1 = tile kt+1 (D=1): U(kt+2) off +64; G,A(kt+3) off +96
        ug_body<1>(As, Gs, Us, pA0, pA1, pG0, pG1, pU0, pU1,
                   64, 96, (kt + 2) < NT, (kt + 3) < NT, wn, r16, kg, wave, ag, au);
        pA0 += 64; pA1 += 64; pG0 += 64; pG1 += 64; pU0 += 64; pU1 += 64;
    }

    // epilogue: in-register SwiGLU, single write of inter
    #pragma unroll
    for (int mi = 0; mi < 8; ++mi)
        #pragma unroll
        for (int ni = 0; ni < 2; ++ni) {
            const int row = m0 + mi * 16 + kg * 4;
            const int col = n0 + wn * 32 + ni * 16 + r16;
            f32x4 g = ag[mi][ni], u = au[mi][ni];
            #pragma unroll
            for (int rr = 0; rr < 4; ++rr) {
                float gv = g[rr];
                float s  = gv / (1.0f + __expf(-gv));
                inter[(size_t)(row + rr) * Id + col] = f2bf(s * u[rr]);
            }
        }
}

// ===========================================================================
// Down GEMM: out = inter . wd^T (fp32 out)
// 128(m)x256(n) tile, BK=32, 256 thr / 4 waves (wave = 64-col slice),
// 2 blocks/CU. 2 phases per K-tile:
//   P1: ds af(8)+bf01(2); stage B(t+1)->Bs[D^1] (4); bar; lgkm0; MFMA ni01; bar.
//   P2: ds bf23(2); stage A(t+2)->As[D] (2); bar; lgkm0; MFMA ni23;
//       vmcnt(2); bar.
// Reader map: Bs[D] read P1+P2 -> next tile's B staged to Bs[D^1] at P1
// (last read of Bs[D^1] completed at previous tile's P2-end barrier);
// As[D] read only P1 -> staged P2. Race-free.
// ===========================================================================
template<int D>
__device__ __forceinline__ void dn_body(
    unsigned short (&As)[2][4096], unsigned short (&Bs)[2][2][4096],
    const unsigned short* pA0, const unsigned short* pA1,
    const unsigned short* const (&pB)[4],
    int stB, int stA, bool pfB, bool pfA,
    int wn, int r16, int kg, int wave,
    f32x4 (&acc)[8][4])
{
    short8 af[8], bf01[2], bf23[2];
    const int bh = wn >> 1;          // B half this wave reads
    const int br = (wn & 1) * 64;    // row base within half

    // ---- P1 ----
    #pragma unroll
    for (int mi = 0; mi < 8; ++mi)
        af[mi] = *(const short8*)&As[D][AOFF32(mi * 16 + r16, kg)];
    #pragma unroll
    for (int ni = 0; ni < 2; ++ni)
        bf01[ni] = *(const short8*)&Bs[D][bh][AOFF32(br + ni * 16 + r16, kg)];
    if (pfB) {
        gload16(pB[0] + stB, &Bs[D ^ 1][0][wave * 512]);
        gload16(pB[1] + stB, &Bs[D ^ 1][0][2048 + wave * 512]);
        gload16(pB[2] + stB, &Bs[D ^ 1][1][wave * 512]);
        gload16(pB[3] + stB, &Bs[D ^ 1][1][2048 + wave * 512]);
    }
    BARRIER();
    LGKM0();
    __builtin_amdgcn_s_setprio(1);
    #pragma unroll
    for (int mi = 0; mi < 8; ++mi)
        #pragma unroll
        for (int ni = 0; ni < 2; ++ni)
            acc[mi][ni] = __builtin_amdgcn_mfma_f32_16x16x32_bf16(af[mi], bf01[ni], acc[mi][ni], 0, 0, 0);
    __builtin_amdgcn_s_setprio(0);
    BARRIER();

    // ---- P2 ----
    #pragma unroll
    for (int ni = 0; ni < 2; ++ni)
        bf23[ni] = *(const short8*)&Bs[D][bh][AOFF32(br + (ni + 2) * 16 + r16, kg)];
    if (pfA) {
        gload16(pA0 + stA, &As[D][wave * 512]);
        gload16(pA1 + stA, &As[D][2048 + wave * 512]);
    }
    BARRIER();
    LGKM0();
    __builtin_amdgcn_s_setprio(1);
    #pragma unroll
    for (int mi = 0; mi < 8; ++mi)
        #pragma unroll
        for (int ni = 0; ni < 2; ++ni)
            acc[mi][ni + 2] = __builtin_amdgcn_mfma_f32_16x16x32_bf16(af[mi], bf23[ni], acc[mi][ni + 2], 0, 0, 0);
    __builtin_amdgcn_s_setprio(0);
    if (pfA) { VMCNT(2); }
    else     { VMCNT(0); }
    BARRIER();
}

__global__ __launch_bounds__(256, 2) void k_down(
    const unsigned short* __restrict__ A, const unsigned short* __restrict__ B,
    float* __restrict__ Cf)
{
    __shared__ unsigned short As[2][4096];     // 16 KiB
    __shared__ unsigned short Bs[2][2][4096];  // 32 KiB ([dbuf][half 128-rows][..])

    const int tid  = threadIdx.x;
    const int wave = tid >> 6;
    const int lane = tid & 63;
    const int wn   = wave;               // 0..3 -> cols wn*64
    const int r16  = lane & 15;
    const int kg   = lane >> 4;
    constexpr int K = Id;                // 11008

    const int nwg = gridDim.x;           // 1024 = 64m x 16n
    const int bid = blockIdx.x;
    const int swz = (bid & 7) * (nwg >> 3) + (bid >> 3);
    const int grp = swz / 128;           // 128 blocks per m-group (8m x 16n)
    const int rem = swz % 128;
    const int m0  = (grp * 8 + (rem & 7)) * 128;
    const int n0  = (rem >> 3) * 256;

    int r0_, kc0_, r1_, kc1_;
    chunk_src(tid, r0_, kc0_);
    chunk_src(256 + tid, r1_, kc1_);
    const unsigned short* pA0 = A + (size_t)(m0 + r0_) * K + kc0_ * 8;
    const unsigned short* pA1 = A + (size_t)(m0 + r1_) * K + kc1_ * 8;
    const unsigned short* pB[4] = {
        B + (size_t)(n0 + r0_) * K + kc0_ * 8,          // half0 pass0
        B + (size_t)(n0 + r1_) * K + kc1_ * 8,          // half0 pass1
        B + (size_t)(n0 + 128 + r0_) * K + kc0_ * 8,    // half1 pass0
        B + (size_t)(n0 + 128 + r1_) * K + kc1_ * 8     // half1 pass1
    };

    f32x4 acc[8][4] = {};

    constexpr int NT = K >> 5;   // 344 (even)

    // prologue: A(0),B(0)->bufs[0]; A(1)->As[1]  (B(1) staged at t=0 P1)
    gload16(pA0, &As[0][wave * 512]);   gload16(pA1, &As[0][2048 + wave * 512]);
    gload16(pB[0], &Bs[0][0][wave * 512]);  gload16(pB[1], &Bs[0][0][2048 + wave * 512]);
    gload16(pB[2], &Bs[0][1][wave * 512]);  gload16(pB[3], &Bs[0][1][2048 + wave * 512]);
    gload16(pA0 + 32, &As[1][wave * 512]);  gload16(pA1 + 32, &As[1][2048 + wave * 512]);
    VMCNT(2);      // tile 0's 6 loads landed; A(1) in flight
    BARRIER();

    for (int kt = 0; kt < NT; kt += 2) {
        dn_body<0>(As, Bs, pA0, pA1, pB, 32, 64, true, (kt + 2) < NT,
                   wn, r16, kg, wave, acc);
        dn_body<1>(As, Bs, pA0, pA1, pB, 64, 96, (kt + 2) < NT, (kt + 3) < NT,
                   wn, r16, kg, wave, acc);
        pA0 += 64; pA1 += 64;
        pB[0] += 64; pB[1] += 64; pB[2] += 64; pB[3] += 64;
    }

    #pragma unroll
    for (int mi = 0; mi < 8; ++mi)
        #pragma unroll
        for (int ni = 0; ni < 4; ++ni) {
            const int row = m0 + mi * 16 + kg * 4;
            const int col = n0 + wn * 64 + ni * 16 + r16;
            f32x4 v = acc[mi][ni];
            #pragma unroll
            for (int rr = 0; rr < 4; ++rr)
                Cf[(size_t)(row + rr) * Hd + col] = v[rr];
        }
}

extern "C" void kernel_launch(void* const* d_in, const int* in_sizes, int n_in,
                              void* d_out, int out_size, void* d_ws, size_t ws_size,
                              hipStream_t stream) {
    const float* x  = (const float*)d_in[0];
    const float* wg = (const float*)d_in[1];
    const float* wu = (const float*)d_in[2];
    const float* wd = (const float*)d_in[3];
    float* out = (float*)d_out;

    // ws layout (total 494.0 MB):
    // [inter: Md*Id bf16][xb: Md*Hd][wgb: Id*Hd][wub: Id*Hd][wdb: Id*Hd]
    unsigned short* inter = (unsigned short*)d_ws;
    unsigned short* xb  = (unsigned short*)((char*)d_ws + (size_t)Md * Id * 2);
    unsigned short* wgb = xb  + (size_t)Md * Hd;
    unsigned short* wub = wgb + (size_t)Id * Hd;
    unsigned short* wdb = wub + (size_t)Id * Hd;

    k_cvt4<<<dim3(2048), dim3(256), 0, stream>>>(
        x,  xb,  Md * Hd / 8,
        wg, wgb, Id * Hd / 8,
        wu, wub, Id * Hd / 8,
        wd, wdb, Id * Hd / 8);

    // fused up+gate: inter = silu(x.wg^T) * (x.wu^T)
    k_upgate<<<dim3((Md / 128) * (Id / 128)), dim3(256), 0, stream>>>(xb, wgb, wub, inter);
    // down: out = inter . wd^T
    k_down<<<dim3((Md / 128) * (Hd / 256)), dim3(256), 0, stream>>>(inter, wdb, out);
}

// Round 11
// 2337.640 us; speedup vs baseline: 1.0557x; 1.0557x over previous
//
#include <hip/hip_runtime.h>
#include <hip/hip_bf16.h>
#include <stdint.h>

// B,S,H,I = 4,2048,4096,11008 ; M = B*S = 8192
static constexpr int Hd = 4096;
static constexpr int Id = 11008;
static constexpr int Md = 8192;

using short8 = __attribute__((ext_vector_type(8))) short;
using f32x4  = __attribute__((ext_vector_type(4))) float;

__device__ __forceinline__ unsigned short f2bf(float x) {
    union { float f; unsigned u; } v; v.f = x;
    unsigned r = v.u + 0x7FFF + ((v.u >> 16) & 1);   // RNE
    return (unsigned short)(r >> 16);
}

typedef const __attribute__((address_space(1))) unsigned int* as1_u32p;
typedef __attribute__((address_space(3))) unsigned int* as3_u32p;

__device__ __forceinline__ void gload16(const unsigned short* g, unsigned short* l) {
    __builtin_amdgcn_global_load_lds((as1_u32p)(const void*)g, (as3_u32p)(void*)l, 16, 0, 0);
}

// swizzled chunk offset (ushort index) within a [rows][64 cols] bf16 tile.
#define AOFF(r, c) ((((r) * 8) + ((c) ^ ((r) & 7))) * 8)

#define LGKM0() do { asm volatile("s_waitcnt lgkmcnt(0)" ::: "memory"); \
                     __builtin_amdgcn_sched_barrier(0); } while (0)
#define LGKMC8() do { asm volatile("s_waitcnt lgkmcnt(8)" ::: "memory"); } while (0)
#define VMCNT(n) do { asm volatile("s_waitcnt vmcnt(" #n ")" ::: "memory"); \
                      __builtin_amdgcn_sched_barrier(0); } while (0)
#define BARRIER() do { asm volatile("" ::: "memory"); __builtin_amdgcn_s_barrier(); \
                       asm volatile("" ::: "memory"); } while (0)

// ---------------------------------------------------------------------------
// fp32 -> bf16 bulk converter: all 4 tensors in one launch
// ---------------------------------------------------------------------------
__global__ __launch_bounds__(256) void k_cvt4(
    const float* __restrict__ s0, unsigned short* __restrict__ d0, int n0,
    const float* __restrict__ s1, unsigned short* __restrict__ d1, int n1,
    const float* __restrict__ s2, unsigned short* __restrict__ d2, int n2,
    const float* __restrict__ s3, unsigned short* __restrict__ d3, int n3)
{
    const int total = n0 + n1 + n2 + n3;
    int i = blockIdx.x * blockDim.x + threadIdx.x;
    const int stride = gridDim.x * blockDim.x;
    for (; i < total; i += stride) {
        const float* s; unsigned short* d; int j = i;
        if (j < n0) { s = s0; d = d0; }
        else { j -= n0;
            if (j < n1) { s = s1; d = d1; }
            else { j -= n1;
                if (j < n2) { s = s2; d = d2; }
                else { j -= n2; s = s3; d = d3; }
            }
        }
        f32x4 a = *(const f32x4*)(s + (size_t)j * 8);
        f32x4 b = *(const f32x4*)(s + (size_t)j * 8 + 4);
        short8 v;
        v[0] = (short)f2bf(a[0]); v[1] = (short)f2bf(a[1]);
        v[2] = (short)f2bf(a[2]); v[3] = (short)f2bf(a[3]);
        v[4] = (short)f2bf(b[0]); v[5] = (short)f2bf(b[1]);
        v[6] = (short)f2bf(b[2]); v[7] = (short)f2bf(b[3]);
        *reinterpret_cast<short8*>(d + (size_t)j * 8) = v;
    }
}

// ===========================================================================
// FUSED up+gate: inter = silu(x.wg^T) * (x.wu^T)
// 256(m)x128(i) tile, BK=64, 8 waves (2m x 4n), wave 128x32 per matrix.
// Even staging: exactly 2 gloads per phase (m201 interleave).
// Reader map per wave: As[D][h] read P1+P3 -> A(t+1)->As[D^1] @P1(h0)/P2(h1)
//   (As[D^1] last read by tile t-1's P3, confirmed by its end barrier);
// Gs[D] read only P1 -> G(t+2) @P3; Us[D] read only P2 -> U(t+2) @P4.
// Issue order Ah0,Ah1,G,U -> VMCNT(4) at P4-end completes A(t+1),G(t+1),
// U(t+1); leaves G,U(t+2) in flight.
// ===========================================================================
template<int D>
__device__ __forceinline__ void ug_body(
    unsigned short (&As)[2][2][8192], unsigned short (&Gs)[2][8192], unsigned short (&Us)[2][8192],
    const unsigned short* pA0, const unsigned short* pA1,
    const unsigned short* pG0, const unsigned short* pG1,
    const unsigned short* pU0, const unsigned short* pU1,
    int stA, int stGU, bool pfA, bool pfGU,
    int wm, int wn, int r16, int kg, int wave,
    f32x4 (&accg)[8][2], f32x4 (&accu)[8][2])
{
    constexpr size_t hK = (size_t)128 * Hd;
    short8 af[4][2], gf[2][2], uf[2][2];

    // ---- P1: stage A(t+1) half0 -> As[D^1][0]; read af mi0-3 + gf; MFMA G ----
    if (pfA) {
        gload16(pA0 + stA, &As[D ^ 1][0][wave * 512]);
        gload16(pA1 + stA, &As[D ^ 1][0][4096 + wave * 512]);
    }
    #pragma unroll
    for (int mi = 0; mi < 4; ++mi)
        #pragma unroll
        for (int kk = 0; kk < 2; ++kk)
            af[mi][kk] = *(const short8*)&As[D][wm][AOFF(mi * 16 + r16, kk * 4 + kg)];
    #pragma unroll
    for (int ni = 0; ni < 2; ++ni)
        #pragma unroll
        for (int kk = 0; kk < 2; ++kk)
            gf[ni][kk] = *(const short8*)&Gs[D][AOFF(wn * 32 + ni * 16 + r16, kk * 4 + kg)];
    LGKMC8();
    BARRIER();
    LGKM0();
    __builtin_amdgcn_s_setprio(1);
    #pragma unroll
    for (int mi = 0; mi < 4; ++mi)
        #pragma unroll
        for (int ni = 0; ni < 2; ++ni)
            #pragma unroll
            for (int kk = 0; kk < 2; ++kk)
                accg[mi][ni] = __builtin_amdgcn_mfma_f32_16x16x32_bf16(af[mi][kk], gf[ni][kk], accg[mi][ni], 0, 0, 0);
    __builtin_amdgcn_s_setprio(0);
    BARRIER();

    // ---- P2: stage A(t+1) half1 -> As[D^1][1]; read uf; MFMA U mi0-3 ----
    if (pfA) {
        gload16(pA0 + hK + stA, &As[D ^ 1][1][wave * 512]);
        gload16(pA1 + hK + stA, &As[D ^ 1][1][4096 + wave * 512]);
    }
    #pragma unroll
    for (int ni = 0; ni < 2; ++ni)
        #pragma unroll
        for (int kk = 0; kk < 2; ++kk)
            uf[ni][kk] = *(const short8*)&Us[D][AOFF(wn * 32 + ni * 16 + r16, kk * 4 + kg)];
    BARRIER();
    LGKM0();
    __builtin_amdgcn_s_setprio(1);
    #pragma unroll
    for (int mi = 0; mi < 4; ++mi)
        #pragma unroll
        for (int ni = 0; ni < 2; ++ni)
            #pragma unroll
            for (int kk = 0; kk < 2; ++kk)
                accu[mi][ni] = __builtin_amdgcn_mfma_f32_16x16x32_bf16(af[mi][kk], uf[ni][kk], accu[mi][ni], 0, 0, 0);
    __builtin_amdgcn_s_setprio(0);
    BARRIER();

    // ---- P3: stage G(t+2) -> Gs[D]; read af mi4-7; MFMA G mi4-7 ----
    if (pfGU) {
        gload16(pG0 + stGU, &Gs[D][wave * 512]);
        gload16(pG1 + stGU, &Gs[D][4096 + wave * 512]);
    }
    #pragma unroll
    for (int mi = 0; mi < 4; ++mi)
        #pragma unroll
        for (int kk = 0; kk < 2; ++kk)
            af[mi][kk] = *(const short8*)&As[D][wm][AOFF((mi + 4) * 16 + r16, kk * 4 + kg)];
    BARRIER();
    LGKM0();
    __builtin_amdgcn_s_setprio(1);
    #pragma unroll
    for (int mi = 0; mi < 4; ++mi)
        #pragma unroll
        for (int ni = 0; ni < 2; ++ni)
            #pragma unroll
            for (int kk = 0; kk < 2; ++kk)
                accg[mi + 4][ni] = __builtin_amdgcn_mfma_f32_16x16x32_bf16(af[mi][kk], gf[ni][kk], accg[mi + 4][ni], 0, 0, 0);
    __builtin_amdgcn_s_setprio(0);
    BARRIER();

    // ---- P4: stage U(t+2) -> Us[D]; MFMA U mi4-7 (regs resident) ----
    if (pfGU) {
        gload16(pU0 + stGU, &Us[D][wave * 512]);
        gload16(pU1 + stGU, &Us[D][4096 + wave * 512]);
    }
    __builtin_amdgcn_s_setprio(1);
    #pragma unroll
    for (int mi = 0; mi < 4; ++mi)
        #pragma unroll
        for (int ni = 0; ni < 2; ++ni)
            #pragma unroll
            for (int kk = 0; kk < 2; ++kk)
                accu[mi + 4][ni] = __builtin_amdgcn_mfma_f32_16x16x32_bf16(af[mi][kk], uf[ni][kk], accu[mi + 4][ni], 0, 0, 0);
    __builtin_amdgcn_s_setprio(0);
    if (pfGU) { VMCNT(4); }
    else      { VMCNT(0); }
    BARRIER();
}

__global__ __launch_bounds__(512, 2) void k_upgate(
    const unsigned short* __restrict__ A,   // xb  [Md][Hd]
    const unsigned short* __restrict__ G,   // wgb [Id][Hd]
    const unsigned short* __restrict__ U,   // wub [Id][Hd]
    unsigned short* __restrict__ inter)     // [Md][Id]
{
    __shared__ unsigned short As[2][2][8192];  // 64 KiB
    __shared__ unsigned short Gs[2][8192];     // 32 KiB
    __shared__ unsigned short Us[2][8192];     // 32 KiB

    const int tid  = threadIdx.x;
    const int wave = tid >> 6;
    const int lane = tid & 63;
    const int wm   = wave >> 2;
    const int wn   = wave & 3;
    const int r16  = lane & 15;
    const int kg   = lane >> 4;

    // raster: XCD chunks; GROUP_M=8 m-tiles, m fastest, n-major.
    const int nwg = gridDim.x;           // 2752 = 32m x 86n
    const int bid = blockIdx.x;
    const int swz = (bid & 7) * (nwg >> 3) + (bid >> 3);
    const int grp = swz / 688;
    const int rem = swz % 688;
    const int m0  = (grp * 8 + (rem & 7)) * 256;
    const int n0  = (rem >> 3) * 128;

    const int i0 = tid,       r0 = i0 >> 3;
    const int i1 = 512 + tid, r1 = i1 >> 3;
    const int cc0 = (i0 & 7) ^ (r0 & 7);
    const int cc1 = (i1 & 7) ^ (r1 & 7);
    constexpr size_t hK = (size_t)128 * Hd;

    const unsigned short* pA0 = A + (size_t)(m0 + r0) * Hd + cc0 * 8;
    const unsigned short* pA1 = A + (size_t)(m0 + r1) * Hd + cc1 * 8;
    const unsigned short* pG0 = G + (size_t)(n0 + r0) * Hd + cc0 * 8;
    const unsigned short* pG1 = G + (size_t)(n0 + r1) * Hd + cc1 * 8;
    const unsigned short* pU0 = U + (size_t)(n0 + r0) * Hd + cc0 * 8;
    const unsigned short* pU1 = U + (size_t)(n0 + r1) * Hd + cc1 * 8;

    f32x4 accg[8][2] = {};
    f32x4 accu[8][2] = {};

    constexpr int NT = Hd >> 6;   // 64 (even)

    // prologue: A(0) full, G(0),U(0), G(1),U(1) = 12 loads.
    // A(1) is staged in the first loop body (P1/P2).
    gload16(pA0,      &As[0][0][wave * 512]);
    gload16(pA1,      &As[0][0][4096 + wave * 512]);
    gload16(pA0 + hK, &As[0][1][wave * 512]);
    gload16(pA1 + hK, &As[0][1][4096 + wave * 512]);
    gload16(pG0,      &Gs[0][wave * 512]);
    gload16(pG1,      &Gs[0][4096 + wave * 512]);
    gload16(pU0,      &Us[0][wave * 512]);
    gload16(pU1,      &Us[0][4096 + wave * 512]);
    gload16(pG0 + 64, &Gs[1][wave * 512]);
    gload16(pG1 + 64, &Gs[1][4096 + wave * 512]);
    gload16(pU0 + 64, &Us[1][wave * 512]);
    gload16(pU1 + 64, &Us[1][4096 + wave * 512]);
    VMCNT(4);      // tile 0 landed; G/U(1) in flight
    BARRIER();

    for (int kt = 0; kt < NT; kt += 2) {
        // body0 = tile kt (D=0): A(kt+1)@+64, G/U(kt+2)@+128
        ug_body<0>(As, Gs, Us, pA0, pA1, pG0, pG1, pU0, pU1,
                   64, 128, true, (kt + 2) < NT, wm, wn, r16, kg, wave, accg, accu);
        // body1 = tile kt+1 (D=1): A(kt+2)@+128, G/U(kt+3)@+192
        ug_body<1>(As, Gs, Us, pA0, pA1, pG0, pG1, pU0, pU1,
                   128, 192, (kt + 2) < NT, (kt + 3) < NT, wm, wn, r16, kg, wave, accg, accu);
        pA0 += 128; pA1 += 128; pG0 += 128; pG1 += 128; pU0 += 128; pU1 += 128;
    }

    // epilogue: in-register SwiGLU, single write of inter
    #pragma unroll
    for (int mi = 0; mi < 8; ++mi)
        #pragma unroll
        for (int ni = 0; ni < 2; ++ni) {
            const int row = m0 + wm * 128 + mi * 16 + kg * 4;
            const int col = n0 + wn * 32 + ni * 16 + r16;
            f32x4 g = accg[mi][ni], u = accu[mi][ni];
            #pragma unroll
            for (int rr = 0; rr < 4; ++rr) {
                float gv = g[rr];
                float s  = gv / (1.0f + __expf(-gv));
                inter[(size_t)(row + rr) * Id + col] = f2bf(s * u[rr]);
            }
        }
}

// ===========================================================================
// Down GEMM: out = inter . wd^T (fp32 out)
// 256x256 tile, BK=64, 8 waves, 4-phase, even 2-gloads-per-phase staging.
// Reader map: Bs[D][h] read P1(b0f)+P2(b1f) -> B(t+2) @P3(h0)/P4(h1);
// As[D][wm] read P1(mi0-3)+P3(mi4-7) -> A(t+1)->As[D^1] @P1(h0)/P2(h1).
// VMCNT(4) at P4-end: completes A(t+1) (t P1/P2) and B(t+1) (t-1 P3/P4);
// leaves B(t+2) halves in flight.
// ===========================================================================
template<int D>
__device__ __forceinline__ void ktile_body(
    unsigned short (&As)[2][2][8192], unsigned short (&Bs)[2][2][8192],
    const unsigned short* pA0, const unsigned short* pA1,
    const unsigned short* pB0, const unsigned short* pB1,
    size_t hK, int stA, int stB, bool pfA, bool pfB,
    int wm, int wn, int r16, int kg, int wave,
    f32x4 (&acc)[8][4], short8 (&af)[4][2], short8 (&b0f)[2][2], short8 (&b1f)[2][2])
{
    // ---- P1: stage A(t+1) half0 -> As[D^1][0]; read af mi0-3 + b0f ----
    if (pfA) {
        gload16(pA0 + stA, &As[D ^ 1][0][wave * 512]);
        gload16(pA1 + stA, &As[D ^ 1][0][4096 + wave * 512]);
    }
    #pragma unroll
    for (int mi = 0; mi < 4; ++mi)
        #pragma unroll
        for (int kk = 0; kk < 2; ++kk)
            af[mi][kk] = *(const short8*)&As[D][wm][AOFF(mi * 16 + r16, kk * 4 + kg)];
    #pragma unroll
    for (int ni = 0; ni < 2; ++ni)
        #pragma unroll
        for (int kk = 0; kk < 2; ++kk)
            b0f[ni][kk] = *(const short8*)&Bs[D][wn >> 1][AOFF((wn & 1) * 64 + ni * 16 + r16, kk * 4 + kg)];
    LGKMC8();
    BARRIER();
    LGKM0();
    __builtin_amdgcn_s_setprio(1);
    #pragma unroll
    for (int mi = 0; mi < 4; ++mi)
        #pragma unroll
        for (int ni = 0; ni < 2; ++ni)
            #pragma unroll
            for (int kk = 0; kk < 2; ++kk)
                acc[mi][ni] = __builtin_amdgcn_mfma_f32_16x16x32_bf16(af[mi][kk], b0f[ni][kk], acc[mi][ni], 0, 0, 0);
    __builtin_amdgcn_s_setprio(0);
    BARRIER();

    // ---- P2: stage A(t+1) half1 -> As[D^1][1]; read b1f ----
    if (pfA) {
        gload16(pA0 + hK + stA, &As[D ^ 1][1][wave * 512]);
        gload16(pA1 + hK + stA, &As[D ^ 1][1][4096 + wave * 512]);
    }
    #pragma unroll
    for (int ni = 0; ni < 2; ++ni)
        #pragma unroll
        for (int kk = 0; kk < 2; ++kk)
            b1f[ni][kk] = *(const short8*)&Bs[D][wn >> 1][AOFF((wn & 1) * 64 + (ni + 2) * 16 + r16, kk * 4 + kg)];
    BARRIER();
    LGKM0();
    __builtin_amdgcn_s_setprio(1);
    #pragma unroll
    for (int mi = 0; mi < 4; ++mi)
        #pragma unroll
        for (int ni = 0; ni < 2; ++ni)
            #pragma unroll
            for (int kk = 0; kk < 2; ++kk)
                acc[mi][ni + 2] = __builtin_amdgcn_mfma_f32_16x16x32_bf16(af[mi][kk], b1f[ni][kk], acc[mi][ni + 2], 0, 0, 0);
    __builtin_amdgcn_s_setprio(0);
    BARRIER();

    // ---- P3: stage B(t+2) half0 -> Bs[D][0]; read af mi4-7 ----
    if (pfB) {
        gload16(pB0 + stB, &Bs[D][0][wave * 512]);
        gload16(pB1 + stB, &Bs[D][0][4096 + wave * 512]);
    }
    #pragma unroll
    for (int mi = 0; mi < 4; ++mi)
        #pragma unroll
        for (int kk = 0; kk < 2; ++kk)
            af[mi][kk] = *(const short8*)&As[D][wm][AOFF((mi + 4) * 16 + r16, kk * 4 + kg)];
    BARRIER();
    LGKM0();
    __builtin_amdgcn_s_setprio(1);
    #pragma unroll
    for (int mi = 0; mi < 4; ++mi)
        #pragma unroll
        for (int ni = 0; ni < 2; ++ni)
            #pragma unroll
            for (int kk = 0; kk < 2; ++kk)
                acc[mi + 4][ni + 2] = __builtin_amdgcn_mfma_f32_16x16x32_bf16(af[mi][kk], b1f[ni][kk], acc[mi + 4][ni + 2], 0, 0, 0);
    __builtin_amdgcn_s_setprio(0);
    BARRIER();

    // ---- P4: stage B(t+2) half1 -> Bs[D][1]; MFMA (regs resident) ----
    if (pfB) {
        gload16(pB0 + hK + stB, &Bs[D][1][wave * 512]);
        gload16(pB1 + hK + stB, &Bs[D][1][4096 + wave * 512]);
    }
    __builtin_amdgcn_s_setprio(1);
    #pragma unroll
    for (int mi = 0; mi < 4; ++mi)
        #pragma unroll
        for (int ni = 0; ni < 2; ++ni)
            #pragma unroll
            for (int kk = 0; kk < 2; ++kk)
                acc[mi + 4][ni] = __builtin_amdgcn_mfma_f32_16x16x32_bf16(af[mi][kk], b0f[ni][kk], acc[mi + 4][ni], 0, 0, 0);
    __builtin_amdgcn_s_setprio(0);
    if (pfB) { VMCNT(4); }
    else     { VMCNT(0); }
    BARRIER();
}

__global__ __launch_bounds__(512, 2) void k_down(
    const unsigned short* __restrict__ A, const unsigned short* __restrict__ B,
    float* __restrict__ Cf, const int K, const int ldC)
{
    __shared__ unsigned short As[2][2][8192];
    __shared__ unsigned short Bs[2][2][8192];

    const int tid  = threadIdx.x;
    const int wave = tid >> 6;
    const int lane = tid & 63;
    const int wm   = wave >> 2;
    const int wn   = wave & 3;
    const int r16  = lane & 15;
    const int kg   = lane >> 4;

    const int nwg = gridDim.x;           // 512 = 32m x 16n
    const int bid = blockIdx.x;
    const int swz = (bid & 7) * (nwg >> 3) + (bid >> 3);
    const int grp = swz / 128;
    const int rem = swz % 128;
    const int m0  = (grp * 8 + (rem & 7)) * 256;
    const int n0  = (rem >> 3) * 256;

    const int i0 = tid,       r0 = i0 >> 3;
    const int i1 = 512 + tid, r1 = i1 >> 3;
    const int cc0 = (i0 & 7) ^ (r0 & 7);
    const int cc1 = (i1 & 7) ^ (r1 & 7);
    const size_t hK = (size_t)128 * K;

    const unsigned short* pA0 = A + (size_t)(m0 + r0) * K + cc0 * 8;
    const unsigned short* pA1 = A + (size_t)(m0 + r1) * K + cc1 * 8;
    const unsigned short* pB0 = B + (size_t)(n0 + r0) * K + cc0 * 8;
    const unsigned short* pB1 = B + (size_t)(n0 + r1) * K + cc1 * 8;

    f32x4 acc[8][4] = {};
    short8 af[4][2], b0f[2][2], b1f[2][2];

    const int NT = K >> 6;   // 172 (even)

    // prologue: A(0) full, B(0) full, B(1) full = 12 loads.
    // A(1) staged in first loop body (P1/P2).
    gload16(pA0,      &As[0][0][wave * 512]);
    gload16(pA1,      &As[0][0][4096 + wave * 512]);
    gload16(pA0 + hK, &As[0][1][wave * 512]);
    gload16(pA1 + hK, &As[0][1][4096 + wave * 512]);
    gload16(pB0,      &Bs[0][0][wave * 512]);
    gload16(pB1,      &Bs[0][0][4096 + wave * 512]);
    gload16(pB0 + hK, &Bs[0][1][wave * 512]);
    gload16(pB1 + hK, &Bs[0][1][4096 + wave * 512]);
    gload16(pB0 + 64,      &Bs[1][0][wave * 512]);
    gload16(pB1 + 64,      &Bs[1][0][4096 + wave * 512]);
    gload16(pB0 + hK + 64, &Bs[1][1][wave * 512]);
    gload16(pB1 + hK + 64, &Bs[1][1][4096 + wave * 512]);
    VMCNT(4);      // tile 0 landed; B(1) in flight
    BARRIER();

    for (int kt = 0; kt < NT; kt += 2) {
        // body0 = tile kt (D=0): A(kt+1)@+64, B(kt+2)@+128
        ktile_body<0>(As, Bs, pA0, pA1, pB0, pB1, hK, 64, 128,
                      true, (kt + 2) < NT, wm, wn, r16, kg, wave, acc, af, b0f, b1f);
        // body1 = tile kt+1 (D=1): A(kt+2)@+128, B(kt+3)@+192
        ktile_body<1>(As, Bs, pA0, pA1, pB0, pB1, hK, 128, 192,
                      (kt + 2) < NT, (kt + 3) < NT, wm, wn, r16, kg, wave, acc, af, b0f, b1f);
        pA0 += 128; pA1 += 128; pB0 += 128; pB1 += 128;
    }

    #pragma unroll
    for (int mi = 0; mi < 8; ++mi)
        #pragma unroll
        for (int ni = 0; ni < 4; ++ni) {
            const int row = m0 + wm * 128 + mi * 16 + kg * 4;
            const int col = n0 + wn * 64 + ni * 16 + r16;
            f32x4 v = acc[mi][ni];
            #pragma unroll
            for (int rr = 0; rr < 4; ++rr)
                Cf[(size_t)(row + rr) * ldC + col] = v[rr];
        }
}

extern "C" void kernel_launch(void* const* d_in, const int* in_sizes, int n_in,
                              void* d_out, int out_size, void* d_ws, size_t ws_size,
                              hipStream_t stream) {
    const float* x  = (const float*)d_in[0];
    const float* wg = (const float*)d_in[1];
    const float* wu = (const float*)d_in[2];
    const float* wd = (const float*)d_in[3];
    float* out = (float*)d_out;

    // ws layout (total 494.0 MB):
    // [inter: Md*Id bf16][xb: Md*Hd][wgb: Id*Hd][wub: Id*Hd][wdb: Id*Hd]
    unsigned short* inter = (unsigned short*)d_ws;
    unsigned short* xb  = (unsigned short*)((char*)d_ws + (size_t)Md * Id * 2);
    unsigned short* wgb = xb  + (size_t)Md * Hd;
    unsigned short* wub = wgb + (size_t)Id * Hd;
    unsigned short* wdb = wub + (size_t)Id * Hd;

    k_cvt4<<<dim3(2048), dim3(256), 0, stream>>>(
        x,  xb,  Md * Hd / 8,
        wg, wgb, Id * Hd / 8,
        wu, wub, Id * Hd / 8,
        wd, wdb, Id * Hd / 8);

    // fused up+gate: inter = silu(x.wg^T) * (x.wu^T)
    k_upgate<<<dim3((Md / 256) * (Id / 128)), dim3(512), 0, stream>>>(xb, wgb, wub, inter);
    // down: out = inter . wd^T
    k_down<<<dim3((Md / 256) * (Hd / 256)), dim3(512), 0, stream>>>(inter, wdb, out, Id, Hd);
}

// Round 12
// 2066.630 us; speedup vs baseline: 1.1942x; 1.1311x over previous
//
#include <hip/hip_runtime.h>
#include <hip/hip_bf16.h>
#include <stdint.h>

// B,S,H,I = 4,2048,4096,11008 ; M = B*S = 8192
static constexpr int Hd = 4096;
static constexpr int Id = 11008;
static constexpr int Md = 8192;

using short8 = __attribute__((ext_vector_type(8))) short;
using f32x4  = __attribute__((ext_vector_type(4))) float;

__device__ __forceinline__ unsigned short f2bf(float x) {
    union { float f; unsigned u; } v; v.f = x;
    unsigned r = v.u + 0x7FFF + ((v.u >> 16) & 1);   // RNE
    return (unsigned short)(r >> 16);
}

typedef const __attribute__((address_space(1))) unsigned int* as1_u32p;
typedef __attribute__((address_space(3))) unsigned int* as3_u32p;

__device__ __forceinline__ void gload16(const unsigned short* g, unsigned short* l) {
    __builtin_amdgcn_global_load_lds((as1_u32p)(const void*)g, (as3_u32p)(void*)l, 16, 0, 0);
}

// swizzled chunk offset (ushort index) within a [rows][64 cols] bf16 tile.
#define AOFF(r, c) ((((r) * 8) + ((c) ^ ((r) & 7))) * 8)

#define LGKM0() do { asm volatile("s_waitcnt lgkmcnt(0)" ::: "memory"); \
                     __builtin_amdgcn_sched_barrier(0); } while (0)
#define LGKMC8() do { asm volatile("s_waitcnt lgkmcnt(8)" ::: "memory"); } while (0)
#define VMCNT(n) do { asm volatile("s_waitcnt vmcnt(" #n ")" ::: "memory"); \
                      __builtin_amdgcn_sched_barrier(0); } while (0)
#define BARRIER() do { asm volatile("" ::: "memory"); __builtin_amdgcn_s_barrier(); \
                       asm volatile("" ::: "memory"); } while (0)

// ---------------------------------------------------------------------------
// fp32 -> bf16 bulk converter: all 4 tensors in one launch
// ---------------------------------------------------------------------------
__global__ __launch_bounds__(256) void k_cvt4(
    const float* __restrict__ s0, unsigned short* __restrict__ d0, int n0,
    const float* __restrict__ s1, unsigned short* __restrict__ d1, int n1,
    const float* __restrict__ s2, unsigned short* __restrict__ d2, int n2,
    const float* __restrict__ s3, unsigned short* __restrict__ d3, int n3)
{
    const int total = n0 + n1 + n2 + n3;
    int i = blockIdx.x * blockDim.x + threadIdx.x;
    const int stride = gridDim.x * blockDim.x;
    for (; i < total; i += stride) {
        const float* s; unsigned short* d; int j = i;
        if (j < n0) { s = s0; d = d0; }
        else { j -= n0;
            if (j < n1) { s = s1; d = d1; }
            else { j -= n1;
                if (j < n2) { s = s2; d = d2; }
                else { j -= n2; s = s3; d = d3; }
            }
        }
        f32x4 a = *(const f32x4*)(s + (size_t)j * 8);
        f32x4 b = *(const f32x4*)(s + (size_t)j * 8 + 4);
        short8 v;
        v[0] = (short)f2bf(a[0]); v[1] = (short)f2bf(a[1]);
        v[2] = (short)f2bf(a[2]); v[3] = (short)f2bf(a[3]);
        v[4] = (short)f2bf(b[0]); v[5] = (short)f2bf(b[1]);
        v[6] = (short)f2bf(b[2]); v[7] = (short)f2bf(b[3]);
        *reinterpret_cast<short8*>(d + (size_t)j * 8) = v;
    }
}

// ===========================================================================
// FUSED up+gate kernel — identical to the proven 2068-us version (R9).
// ===========================================================================
template<int D>
__device__ __forceinline__ void ug_body(
    unsigned short (&As)[2][2][8192], unsigned short (&Gs)[2][8192], unsigned short (&Us)[2][8192],
    const unsigned short* pA0, const unsigned short* pA1,
    const unsigned short* pG0, const unsigned short* pG1,
    const unsigned short* pU0, const unsigned short* pU1,
    int stoff, bool pf,
    int wm, int wn, int r16, int kg, int wave,
    f32x4 (&accg)[8][2], f32x4 (&accu)[8][2])
{
    constexpr size_t hK = (size_t)128 * Hd;
    short8 af[4][2], gf[2][2], uf[2][2];

    // ---- P1 ----
    #pragma unroll
    for (int mi = 0; mi < 4; ++mi)
        #pragma unroll
        for (int kk = 0; kk < 2; ++kk)
            af[mi][kk] = *(const short8*)&As[D][wm][AOFF(mi * 16 + r16, kk * 4 + kg)];
    #pragma unroll
    for (int ni = 0; ni < 2; ++ni)
        #pragma unroll
        for (int kk = 0; kk < 2; ++kk)
            gf[ni][kk] = *(const short8*)&Gs[D][AOFF(wn * 32 + ni * 16 + r16, kk * 4 + kg)];
    LGKMC8();
    BARRIER();
    LGKM0();
    __builtin_amdgcn_s_setprio(1);
    #pragma unroll
    for (int mi = 0; mi < 4; ++mi)
        #pragma unroll
        for (int ni = 0; ni < 2; ++ni)
            #pragma unroll
            for (int kk = 0; kk < 2; ++kk)
                accg[mi][ni] = __builtin_amdgcn_mfma_f32_16x16x32_bf16(af[mi][kk], gf[ni][kk], accg[mi][ni], 0, 0, 0);
    __builtin_amdgcn_s_setprio(0);
    BARRIER();

    // ---- P2: stage G(t+2); read uf; MFMA U mi0-3 ----
    if (pf) {
        gload16(pG0 + stoff, &Gs[D][wave * 512]);
        gload16(pG1 + stoff, &Gs[D][4096 + wave * 512]);
    }
    #pragma unroll
    for (int ni = 0; ni < 2; ++ni)
        #pragma unroll
        for (int kk = 0; kk < 2; ++kk)
            uf[ni][kk] = *(const short8*)&Us[D][AOFF(wn * 32 + ni * 16 + r16, kk * 4 + kg)];
    BARRIER();
    LGKM0();
    __builtin_amdgcn_s_setprio(1);
    #pragma unroll
    for (int mi = 0; mi < 4; ++mi)
        #pragma unroll
        for (int ni = 0; ni < 2; ++ni)
            #pragma unroll
            for (int kk = 0; kk < 2; ++kk)
                accu[mi][ni] = __builtin_amdgcn_mfma_f32_16x16x32_bf16(af[mi][kk], uf[ni][kk], accu[mi][ni], 0, 0, 0);
    __builtin_amdgcn_s_setprio(0);
    BARRIER();

    // ---- P3: stage U(t+2); read af mi4-7; MFMA G mi4-7 ----
    if (pf) {
        gload16(pU0 + stoff, &Us[D][wave * 512]);
        gload16(pU1 + stoff, &Us[D][4096 + wave * 512]);
    }
    #pragma unroll
    for (int mi = 0; mi < 4; ++mi)
        #pragma unroll
        for (int kk = 0; kk < 2; ++kk)
            af[mi][kk] = *(const short8*)&As[D][wm][AOFF((mi + 4) * 16 + r16, kk * 4 + kg)];
    BARRIER();
    LGKM0();
    __builtin_amdgcn_s_setprio(1);
    #pragma unroll
    for (int mi = 0; mi < 4; ++mi)
        #pragma unroll
        for (int ni = 0; ni < 2; ++ni)
            #pragma unroll
            for (int kk = 0; kk < 2; ++kk)
                accg[mi + 4][ni] = __builtin_amdgcn_mfma_f32_16x16x32_bf16(af[mi][kk], gf[ni][kk], accg[mi + 4][ni], 0, 0, 0);
    __builtin_amdgcn_s_setprio(0);
    BARRIER();

    // ---- P4: stage A(t+2); MFMA U mi4-7 ----
    if (pf) {
        gload16(pA0 + stoff,      &As[D][0][wave * 512]);
        gload16(pA1 + stoff,      &As[D][0][4096 + wave * 512]);
        gload16(pA0 + hK + stoff, &As[D][1][wave * 512]);
        gload16(pA1 + hK + stoff, &As[D][1][4096 + wave * 512]);
    }
    __builtin_amdgcn_s_setprio(1);
    #pragma unroll
    for (int mi = 0; mi < 4; ++mi)
        #pragma unroll
        for (int ni = 0; ni < 2; ++ni)
            #pragma unroll
            for (int kk = 0; kk < 2; ++kk)
                accu[mi + 4][ni] = __builtin_amdgcn_mfma_f32_16x16x32_bf16(af[mi][kk], uf[ni][kk], accu[mi + 4][ni], 0, 0, 0);
    __builtin_amdgcn_s_setprio(0);
    if (pf) { VMCNT(8); }
    else    { VMCNT(0); }
    BARRIER();
}

__global__ __launch_bounds__(512, 2) void k_upgate(
    const unsigned short* __restrict__ A,
    const unsigned short* __restrict__ G,
    const unsigned short* __restrict__ U,
    unsigned short* __restrict__ inter)
{
    __shared__ unsigned short As[2][2][8192];
    __shared__ unsigned short Gs[2][8192];
    __shared__ unsigned short Us[2][8192];

    const int tid  = threadIdx.x;
    const int wave = tid >> 6;
    const int lane = tid & 63;
    const int wm   = wave >> 2;
    const int wn   = wave & 3;
    const int r16  = lane & 15;
    const int kg   = lane >> 4;

    const int nwg = gridDim.x;           // 2752
    const int bid = blockIdx.x;
    const int swz = (bid & 7) * (nwg >> 3) + (bid >> 3);
    const int grp = swz / 688;
    const int rem = swz % 688;
    const int m0  = (grp * 8 + (rem & 7)) * 256;
    const int n0  = (rem >> 3) * 128;

    const int i0 = tid,       r0 = i0 >> 3;
    const int i1 = 512 + tid, r1 = i1 >> 3;
    const int cc0 = (i0 & 7) ^ (r0 & 7);
    const int cc1 = (i1 & 7) ^ (r1 & 7);
    constexpr size_t hK = (size_t)128 * Hd;

    const unsigned short* pA0 = A + (size_t)(m0 + r0) * Hd + cc0 * 8;
    const unsigned short* pA1 = A + (size_t)(m0 + r1) * Hd + cc1 * 8;
    const unsigned short* pG0 = G + (size_t)(n0 + r0) * Hd + cc0 * 8;
    const unsigned short* pG1 = G + (size_t)(n0 + r1) * Hd + cc1 * 8;
    const unsigned short* pU0 = U + (size_t)(n0 + r0) * Hd + cc0 * 8;
    const unsigned short* pU1 = U + (size_t)(n0 + r1) * Hd + cc1 * 8;

    f32x4 accg[8][2] = {};
    f32x4 accu[8][2] = {};

    constexpr int NT = Hd >> 6;   // 64

    // prologue: tile 0 (A,G,U) + tile 1 (A,G,U) = 16 loads
    gload16(pA0,      &As[0][0][wave * 512]);
    gload16(pA1,      &As[0][0][4096 + wave * 512]);
    gload16(pA0 + hK, &As[0][1][wave * 512]);
    gload16(pA1 + hK, &As[0][1][4096 + wave * 512]);
    gload16(pG0,      &Gs[0][wave * 512]);
    gload16(pG1,      &Gs[0][4096 + wave * 512]);
    gload16(pU0,      &Us[0][wave * 512]);
    gload16(pU1,      &Us[0][4096 + wave * 512]);
    gload16(pA0 + 64,      &As[1][0][wave * 512]);
    gload16(pA1 + 64,      &As[1][0][4096 + wave * 512]);
    gload16(pA0 + hK + 64, &As[1][1][wave * 512]);
    gload16(pA1 + hK + 64, &As[1][1][4096 + wave * 512]);
    gload16(pG0 + 64, &Gs[1][wave * 512]);
    gload16(pG1 + 64, &Gs[1][4096 + wave * 512]);
    gload16(pU0 + 64, &Us[1][wave * 512]);
    gload16(pU1 + 64, &Us[1][4096 + wave * 512]);
    VMCNT(8);      // tile 0 landed; tile 1 in flight
    BARRIER();

    for (int kt = 0; kt < NT; kt += 2) {
        const bool pf0 = (kt + 2) < NT;
        const bool pf1 = (kt + 3) < NT;
        ug_body<0>(As, Gs, Us, pA0, pA1, pG0, pG1, pU0, pU1,
                   128, pf0, wm, wn, r16, kg, wave, accg, accu);
        ug_body<1>(As, Gs, Us, pA0, pA1, pG0, pG1, pU0, pU1,
                   192, pf1, wm, wn, r16, kg, wave, accg, accu);
        pA0 += 128; pA1 += 128; pG0 += 128; pG1 += 128; pU0 += 128; pU1 += 128;
    }

    #pragma unroll
    for (int mi = 0; mi < 8; ++mi)
        #pragma unroll
        for (int ni = 0; ni < 2; ++ni) {
            const int row = m0 + wm * 128 + mi * 16 + kg * 4;
            const int col = n0 + wn * 32 + ni * 16 + r16;
            f32x4 g = accg[mi][ni], u = accu[mi][ni];
            #pragma unroll
            for (int rr = 0; rr < 4; ++rr) {
                float gv = g[rr];
                float s  = gv / (1.0f + __expf(-gv));
                inter[(size_t)(row + rr) * Id + col] = f2bf(s * u[rr]);
            }
        }
}

// ===========================================================================
// Down GEMM — R9 structure; VMCNT ledger fix: body/prologue VMCNT(4)->(8).
// Bs[D] read P1+P2 -> B(t+2)@P3; As[D] read P1+P3 -> A(t+2)@P4.
// At t-P4-end outstanding = A(t+1)[(t-1)P4] + B(t+2)[t-P3] + A(t+2)[t-P4].
// t+1 needs only A(t+1) drained (B(t+1) older, FIFO) -> VMCNT(8), which
// never waits loads younger than 4 phases.
// ===========================================================================
template<int D>
__device__ __forceinline__ void ktile_body(
    unsigned short (&As)[2][2][8192], unsigned short (&Bs)[2][2][8192],
    const unsigned short* pA0, const unsigned short* pA1,
    const unsigned short* pB0, const unsigned short* pB1,
    size_t hK, int stoff, bool pf,
    int wm, int wn, int r16, int kg, int wave,
    f32x4 (&acc)[8][4], short8 (&af)[4][2], short8 (&b0f)[2][2], short8 (&b1f)[2][2])
{
    // ---- P1 ----
    #pragma unroll
    for (int mi = 0; mi < 4; ++mi)
        #pragma unroll
        for (int kk = 0; kk < 2; ++kk)
            af[mi][kk] = *(const short8*)&As[D][wm][AOFF(mi * 16 + r16, kk * 4 + kg)];
    #pragma unroll
    for (int ni = 0; ni < 2; ++ni)
        #pragma unroll
        for (int kk = 0; kk < 2; ++kk)
            b0f[ni][kk] = *(const short8*)&Bs[D][wn >> 1][AOFF((wn & 1) * 64 + ni * 16 + r16, kk * 4 + kg)];
    LGKMC8();
    BARRIER();
    LGKM0();
    __builtin_amdgcn_s_setprio(1);
    #pragma unroll
    for (int mi = 0; mi < 4; ++mi)
        #pragma unroll
        for (int ni = 0; ni < 2; ++ni)
            #pragma unroll
            for (int kk = 0; kk < 2; ++kk)
                acc[mi][ni] = __builtin_amdgcn_mfma_f32_16x16x32_bf16(af[mi][kk], b0f[ni][kk], acc[mi][ni], 0, 0, 0);
    __builtin_amdgcn_s_setprio(0);
    BARRIER();

    // ---- P2 ----
    #pragma unroll
    for (int ni = 0; ni < 2; ++ni)
        #pragma unroll
        for (int kk = 0; kk < 2; ++kk)
            b1f[ni][kk] = *(const short8*)&Bs[D][wn >> 1][AOFF((wn & 1) * 64 + (ni + 2) * 16 + r16, kk * 4 + kg)];
    BARRIER();
    LGKM0();
    __builtin_amdgcn_s_setprio(1);
    #pragma unroll
    for (int mi = 0; mi < 4; ++mi)
        #pragma unroll
        for (int ni = 0; ni < 2; ++ni)
            #pragma unroll
            for (int kk = 0; kk < 2; ++kk)
                acc[mi][ni + 2] = __builtin_amdgcn_mfma_f32_16x16x32_bf16(af[mi][kk], b1f[ni][kk], acc[mi][ni + 2], 0, 0, 0);
    __builtin_amdgcn_s_setprio(0);
    BARRIER();

    // ---- P3: stage B(t+2); read af mi4-7 ----
    if (pf) {
        gload16(pB0 + stoff,      &Bs[D][0][wave * 512]);
        gload16(pB1 + stoff,      &Bs[D][0][4096 + wave * 512]);
        gload16(pB0 + hK + stoff, &Bs[D][1][wave * 512]);
        gload16(pB1 + hK + stoff, &Bs[D][1][4096 + wave * 512]);
    }
    #pragma unroll
    for (int mi = 0; mi < 4; ++mi)
        #pragma unroll
        for (int kk = 0; kk < 2; ++kk)
            af[mi][kk] = *(const short8*)&As[D][wm][AOFF((mi + 4) * 16 + r16, kk * 4 + kg)];
    BARRIER();
    LGKM0();
    __builtin_amdgcn_s_setprio(1);
    #pragma unroll
    for (int mi = 0; mi < 4; ++mi)
        #pragma unroll
        for (int ni = 0; ni < 2; ++ni)
            #pragma unroll
            for (int kk = 0; kk < 2; ++kk)
                acc[mi + 4][ni + 2] = __builtin_amdgcn_mfma_f32_16x16x32_bf16(af[mi][kk], b1f[ni][kk], acc[mi + 4][ni + 2], 0, 0, 0);
    __builtin_amdgcn_s_setprio(0);
    BARRIER();

    // ---- P4: stage A(t+2); MFMA from regs ----
    if (pf) {
        gload16(pA0 + stoff,      &As[D][0][wave * 512]);
        gload16(pA1 + stoff,      &As[D][0][4096 + wave * 512]);
        gload16(pA0 + hK + stoff, &As[D][1][wave * 512]);
        gload16(pA1 + hK + stoff, &As[D][1][4096 + wave * 512]);
    }
    __builtin_amdgcn_s_setprio(1);
    #pragma unroll
    for (int mi = 0; mi < 4; ++mi)
        #pragma unroll
        for (int ni = 0; ni < 2; ++ni)
            #pragma unroll
            for (int kk = 0; kk < 2; ++kk)
                acc[mi + 4][ni] = __builtin_amdgcn_mfma_f32_16x16x32_bf16(af[mi][kk], b0f[ni][kk], acc[mi + 4][ni], 0, 0, 0);
    __builtin_amdgcn_s_setprio(0);
    if (pf) { VMCNT(8); }   // FIX: drain only A(t+1); leave t+2 streams flying
    else    { VMCNT(0); }
    BARRIER();
}

__global__ __launch_bounds__(512, 2) void k_down(
    const unsigned short* __restrict__ A, const unsigned short* __restrict__ B,
    float* __restrict__ Cf, const int K, const int ldC)
{
    __shared__ unsigned short As[2][2][8192];
    __shared__ unsigned short Bs[2][2][8192];

    const int tid  = threadIdx.x;
    const int wave = tid >> 6;
    const int lane = tid & 63;
    const int wm   = wave >> 2;
    const int wn   = wave & 3;
    const int r16  = lane & 15;
    const int kg   = lane >> 4;

    const int nwg = gridDim.x;           // 512
    const int bid = blockIdx.x;
    const int swz = (bid & 7) * (nwg >> 3) + (bid >> 3);
    const int grp = swz / 128;
    const int rem = swz % 128;
    const int m0  = (grp * 8 + (rem & 7)) * 256;
    const int n0  = (rem >> 3) * 256;

    const int i0 = tid,       r0 = i0 >> 3;
    const int i1 = 512 + tid, r1 = i1 >> 3;
    const int cc0 = (i0 & 7) ^ (r0 & 7);
    const int cc1 = (i1 & 7) ^ (r1 & 7);
    const size_t hK = (size_t)128 * K;

    const unsigned short* pA0 = A + (size_t)(m0 + r0) * K + cc0 * 8;
    const unsigned short* pA1 = A + (size_t)(m0 + r1) * K + cc1 * 8;
    const unsigned short* pB0 = B + (size_t)(n0 + r0) * K + cc0 * 8;
    const unsigned short* pB1 = B + (size_t)(n0 + r1) * K + cc1 * 8;

    f32x4 acc[8][4] = {};
    short8 af[4][2], b0f[2][2], b1f[2][2];

    const int NT = K >> 6;   // 172

    gload16(pA0,      &As[0][0][wave * 512]);
    gload16(pA1,      &As[0][0][4096 + wave * 512]);
    gload16(pA0 + hK, &As[0][1][wave * 512]);
    gload16(pA1 + hK, &As[0][1][4096 + wave * 512]);
    gload16(pB0,      &Bs[0][0][wave * 512]);
    gload16(pB1,      &Bs[0][0][4096 + wave * 512]);
    gload16(pB0 + hK, &Bs[0][1][wave * 512]);
    gload16(pB1 + hK, &Bs[0][1][4096 + wave * 512]);
    gload16(pA0 + 64,      &As[1][0][wave * 512]);
    gload16(pA1 + 64,      &As[1][0][4096 + wave * 512]);
    gload16(pA0 + hK + 64, &As[1][1][wave * 512]);
    gload16(pA1 + hK + 64, &As[1][1][4096 + wave * 512]);
    gload16(pB0 + 64,      &Bs[1][0][wave * 512]);
    gload16(pB1 + 64,      &Bs[1][0][4096 + wave * 512]);
    gload16(pB0 + hK + 64, &Bs[1][1][wave * 512]);
    gload16(pB1 + hK + 64, &Bs[1][1][4096 + wave * 512]);
    VMCNT(8);      // FIX: tile 0 landed; tile 1 stays in flight
    BARRIER();

    for (int kt = 0; kt < NT; kt += 2) {
        const bool pf0 = (kt + 2) < NT;
        const bool pf1 = (kt + 3) < NT;
        ktile_body<0>(As, Bs, pA0, pA1, pB0, pB1, hK, 128, pf0,
                      wm, wn, r16, kg, wave, acc, af, b0f, b1f);
        ktile_body<1>(As, Bs, pA0, pA1, pB0, pB1, hK, 192, pf1,
                      wm, wn, r16, kg, wave, acc, af, b0f, b1f);
        pA0 += 128; pA1 += 128; pB0 += 128; pB1 += 128;
    }

    #pragma unroll
    for (int mi = 0; mi < 8; ++mi)
        #pragma unroll
        for (int ni = 0; ni < 4; ++ni) {
            const int row = m0 + wm * 128 + mi * 16 + kg * 4;
            const int col = n0 + wn * 64 + ni * 16 + r16;
            f32x4 v = acc[mi][ni];
            #pragma unroll
            for (int rr = 0; rr < 4; ++rr)
                Cf[(size_t)(row + rr) * ldC + col] = v[rr];
        }
}

extern "C" void kernel_launch(void* const* d_in, const int* in_sizes, int n_in,
                              void* d_out, int out_size, void* d_ws, size_t ws_size,
                              hipStream_t stream) {
    const float* x  = (const float*)d_in[0];
    const float* wg = (const float*)d_in[1];
    const float* wu = (const float*)d_in[2];
    const float* wd = (const float*)d_in[3];
    float* out = (float*)d_out;

    unsigned short* inter = (unsigned short*)d_ws;
    unsigned short* xb  = (unsigned short*)((char*)d_ws + (size_t)Md * Id * 2);
    unsigned short* wgb = xb  + (size_t)Md * Hd;
    unsigned short* wub = wgb + (size_t)Id * Hd;
    unsigned short* wdb = wub + (size_t)Id * Hd;

    k_cvt4<<<dim3(2048), dim3(256), 0, stream>>>(
        x,  xb,  Md * Hd / 8,
        wg, wgb, Id * Hd / 8,
        wu, wub, Id * Hd / 8,
        wd, wdb, Id * Hd / 8);

    k_upgate<<<dim3((Md / 256) * (Id / 128)), dim3(512), 0, stream>>>(xb, wgb, wub, inter);
    k_down<<<dim3((Md / 256) * (Hd / 256)), dim3(512), 0, stream>>>(inter, wdb, out, Id, Hd);
}